// Round 12
// baseline (259.770 us; speedup 1.0000x reference)
//
#include <hip/hip_runtime.h>

typedef float  f32x4  __attribute__((ext_vector_type(4)));
typedef short  bf16x8 __attribute__((ext_vector_type(8)));

#define TWOLOG2E   2.8853900817779268f
#define NLOG2E    -1.4426950408889634f
#define NTWOLOG2E -2.8853900817779268f

__device__ __forceinline__ unsigned short f2b(float f) {      // fp32 -> bf16 RNE
    unsigned int u = __builtin_bit_cast(unsigned int, f);
    u += 0x7fffu + ((u >> 16) & 1u);
    return (unsigned short)(u >> 16);
}
__device__ __forceinline__ float b2f(unsigned short s) {
    unsigned int u = ((unsigned int)s) << 16;
    return __builtin_bit_cast(float, u);
}
__device__ __forceinline__ unsigned int pk2(float lo, float hi) {
#if __has_builtin(__builtin_amdgcn_cvt_pk_bf16_f32)
    typedef __bf16 bf16x2 __attribute__((ext_vector_type(2)));
    bf16x2 p = __builtin_amdgcn_cvt_pk_bf16_f32(lo, hi);
    return __builtin_bit_cast(unsigned int, p);
#else
    return (unsigned int)f2b(lo) | ((unsigned int)f2b(hi) << 16);
#endif
}
__device__ __forceinline__ float frcp(float x) { return __builtin_amdgcn_rcpf(x); }
__device__ __forceinline__ float fex2(float x) { return __builtin_amdgcn_exp2f(x); }

// FULLY DECOUPLED formulation: block = 1 wave = 64 threads; each wave owns 16
// batch rows and runs them through ALL 4 layers, t = 0..63, with the complete
// weight set (4 layers x 16 B-frags = 256 VGPRs) resident in registers.
// __launch_bounds__(64,1) -> 512-VGPR budget, 1 wave/SIMD, grid 1024 = exactly
// 4 blocks/CU. NO barriers, NO inter-wave deps, NO pipeline fill/drain.
// h_l lives in per-block LDS (A-frag layout, 16 rows x 40-short stride,
// single-buffered: tile (t,l) reads h_l(t-1) before overwriting with h_l(t);
// same-wave DS ops are in-order so this is race-free). Recurrent MFMA issues
// FIRST (its operand h_l(t-1) is old) to cover the h_{l-1}(t) LDS round-trip.
// Epilogue per cell: 5 exp + 2 rcp (merged-rcp shared-denominator algebra),
// cell state pre-scaled (cp = -2log2e*c); bias rides the MFMA C operand.
__global__ __launch_bounds__(64, 1)
void lstm_mfma(const float* __restrict__ xg,  const float* __restrict__ Wih0,
               const float* __restrict__ Wih, const float* __restrict__ Whh,
               const float* __restrict__ bih, const float* __restrict__ bhh,
               const float* __restrict__ Wlin,const float* __restrict__ blin,
               float* __restrict__ out) {
    __shared__ short        hbuf[4 * 640] __attribute__((aligned(16))); // [l][16row*40]
    __shared__ unsigned int xb[64 * 16];                                // [t][row] 2xbf16

    const int lane = threadIdx.x;      // 0..63
    const int m    = lane & 15;        // A-row / D-col index
    const int q    = lane >> 4;        // quad
    const int row0 = blockIdx.x * 16;

    // zero h buffers (t = -1 state)
    for (int i = lane; i < 1280; i += 64) ((unsigned int*)hbuf)[i] = 0u;

    // stage x -> LDS bf16 [t][row]
    for (int i = lane; i < 1024; i += 64) {
        int r = i >> 6, t = i & 63;
        float x0 = xg[(size_t)(row0 + r) * 192 + t];
        float x1 = xg[(size_t)(row0 + r) * 192 + 64 + t];
        xb[t * 16 + r] = pk2(x0, x1);
    }

    // ---- one-time gather: B-frags + bias for ALL 4 layers (negated scales) ----
    // tile g: gate T=g>>1 of unit 2m+(g&1); rowG = T*32 + 2m + (g&1).
    // layer 0: k<2 = W_ih0 cols, k in [2,32) = 0, k>=32 = W_hh[0].
    bf16x8 bfr[4][8][2];
    float  bv[4][8];
#pragma unroll
    for (int l = 0; l < 4; ++l) {
#pragma unroll
        for (int g = 0; g < 8; ++g) {
            const int   T    = g >> 1;
            const int   rowG = T * 32 + 2 * m + (g & 1);
            const float sc   = (T == 2) ? NTWOLOG2E : NLOG2E;
            bv[l][g] = (bih[l * 128 + rowG] + bhh[l * 128 + rowG]) * sc;
#pragma unroll
            for (int c = 0; c < 2; ++c) {
                const int k0 = c * 32 + q * 8;
                float w[8];
                if (l == 0) {
                    if (c == 0) {
#pragma unroll
                        for (int jj = 0; jj < 8; ++jj) w[jj] = 0.0f;
                        if (q == 0) { w[0] = Wih0[rowG * 2]; w[1] = Wih0[rowG * 2 + 1]; }
                    } else {
                        const float* src = Whh + rowG * 32 + (k0 - 32);
#pragma unroll
                        for (int jj = 0; jj < 8; ++jj) w[jj] = src[jj];
                    }
                } else {
                    const float* src = (c == 0) ? (Wih + (l - 1) * 4096 + rowG * 32 + k0)
                                                : (Whh + l * 4096 + rowG * 32 + (k0 - 32));
#pragma unroll
                    for (int jj = 0; jj < 8; ++jj) w[jj] = src[jj];
                }
                bf16x8 fr;
#pragma unroll
                for (int jj = 0; jj < 8; ++jj) fr[jj] = (short)f2b(w[jj] * sc);
                bfr[l][g][c] = fr;
            }
        }
    }

    float cp[4][2][4];   // scaled cell state -2log2e*c: [l][hf][r]
#pragma unroll
    for (int l = 0; l < 4; ++l)
#pragma unroll
        for (int hf = 0; hf < 2; ++hf)
#pragma unroll
            for (int r = 0; r < 4; ++r) cp[l][hf][r] = 0.0f;

    __syncthreads();   // single-wave: just orders staging writes vs loop reads

    const int aoff = m * 40 + q * 8;   // A-frag byte-lane offset (shorts)

    for (int t = 0; t < 64; ++t) {
#pragma unroll
        for (int l = 0; l < 4; ++l) {
            // recurrent operand first: h_l(t-1), written 4 tile-steps ago
            bf16x8 a1 = *(const bf16x8*)(hbuf + l * 640 + aoff);
            bf16x8 a0;
            if (l == 0) {
                unsigned int xd = xb[t * 16 + m];
                union { unsigned int u[4]; bf16x8 v; } au;
                au.u[0] = (q == 0) ? xd : 0u; au.u[1] = 0u; au.u[2] = 0u; au.u[3] = 0u;
                a0 = au.v;
            } else {
                a0 = *(const bf16x8*)(hbuf + (l - 1) * 640 + aoff);  // h_{l-1}(t), just written
            }

            f32x4 acc[8];
#pragma unroll
            for (int g = 0; g < 8; ++g) {   // recurrent MFMA first (old operand)
                f32x4 cb = {bv[l][g], bv[l][g], bv[l][g], bv[l][g]};
                acc[g] = __builtin_amdgcn_mfma_f32_16x16x32_bf16(a1, bfr[l][g][1], cb, 0, 0, 0);
            }
#pragma unroll
            for (int g = 0; g < 8; ++g)
                acc[g] = __builtin_amdgcn_mfma_f32_16x16x32_bf16(a0, bfr[l][g][0], acc[g], 0, 0, 0);

            unsigned int* hw = (unsigned int*)(hbuf + l * 640);
            float h0[4];
#pragma unroll
            for (int hf = 0; hf < 2; ++hf) {
#pragma unroll
                for (int r = 0; r < 4; ++r) {
                    float ei = fex2(acc[0 + hf][r]);          // e^{-a_i}
                    float ef = fex2(acc[2 + hf][r]);          // e^{-a_f}
                    float eg = fex2(acc[4 + hf][r]);          // e^{-2 a_g}
                    float eo = fex2(acc[6 + hf][r]);          // e^{-a_o}
                    float ap_f = 1.0f + ef;
                    float p1   = (1.0f + ei) * (1.0f + eg);
                    float R_   = frcp(p1 * ap_f);
                    float egp  = __builtin_fmaf(eg, TWOLOG2E, NTWOLOG2E); // -2log2e*(1-eg)
                    float t1   = egp * ap_f;
                    float t2   = __builtin_fmaf(cp[l][hf][r], p1, t1);
                    float cn   = t2 * R_;                     // scaled cell state
                    cp[l][hf][r] = cn;
                    float ec = fex2(cn);                      // e^{-2c}
                    float Rh = frcp((1.0f + eo) * (1.0f + ec));
                    float hh = (1.0f - ec) * Rh;
                    if (hf == 0) h0[r] = hh;
                    else hw[(q * 4 + r) * 20 + m] = pk2(h0[r], hh);  // h_l(t), units 2m|2m+1
                }
            }
        }
    }

    // output head: h3(t=63) in hbuf[3]
    if (lane < 16) {
        const short* h3 = hbuf + 3 * 640 + lane * 40;
        float s = blin[0];
#pragma unroll
        for (int k = 0; k < 32; ++k)
            s += Wlin[k] * b2f((unsigned short)h3[k]);
        out[row0 + lane] = frcp(1.0f + fex2(s * NLOG2E));
    }
}

extern "C" void kernel_launch(void* const* d_in, const int* in_sizes, int n_in,
                              void* d_out, int out_size, void* d_ws, size_t ws_size,
                              hipStream_t stream) {
    const float* x    = (const float*)d_in[0];
    const float* Wih0 = (const float*)d_in[1];
    const float* Wih  = (const float*)d_in[2];
    const float* Whh  = (const float*)d_in[3];
    const float* bih  = (const float*)d_in[4];
    const float* bhh  = (const float*)d_in[5];
    const float* Wlin = (const float*)d_in[6];
    const float* blin = (const float*)d_in[7];
    float* out = (float*)d_out;

    lstm_mfma<<<1024, 64, 0, stream>>>(x, Wih0, Wih, Whh, bih, bhh, Wlin, blin, out);
}